// Round 3
// baseline (266.541 us; speedup 1.0000x reference)
//
#include <hip/hip_runtime.h>
#include <hip/hip_bf16.h>
#include <stdint.h>

#define NROWS 8192
#define NDIM  512
#define MARGIN 0.3f
#define TGRID 128                 // 8192 / 64 tile rows
#define NT    (TGRID*(TGRID+1)/2) // 8256 upper-triangular 64x64 tiles

typedef __attribute__((ext_vector_type(4))) float floatx4;
typedef __attribute__((ext_vector_type(8))) short shortx8;

__device__ inline unsigned short f32_to_bf16_bits(float x) {
  union { float f; unsigned int u; } v; v.f = x;
  unsigned int r = v.u + 0x7FFFu + ((v.u >> 16) & 1u);  // RNE
  return (unsigned short)(r >> 16);
}

// fp32 -> bf16, 16 floats per thread; also zeroes the (poisoned) output scalar
__global__ void convert_kernel(const float4* __restrict__ in, shortx8* __restrict__ out,
                               float* __restrict__ loss_out) {
  int i = blockIdx.x * blockDim.x + threadIdx.x;
  if (i == 0) loss_out[0] = 0.f;
  float4 f[4];
#pragma unroll
  for (int j = 0; j < 4; j++) f[j] = in[i * 4 + j];
  shortx8 o0, o1;
#pragma unroll
  for (int j = 0; j < 2; j++) {
    o0[j*4+0] = (short)f32_to_bf16_bits(f[j].x);
    o0[j*4+1] = (short)f32_to_bf16_bits(f[j].y);
    o0[j*4+2] = (short)f32_to_bf16_bits(f[j].z);
    o0[j*4+3] = (short)f32_to_bf16_bits(f[j].w);
    o1[j*4+0] = (short)f32_to_bf16_bits(f[j+2].x);
    o1[j*4+1] = (short)f32_to_bf16_bits(f[j+2].y);
    o1[j*4+2] = (short)f32_to_bf16_bits(f[j+2].z);
    o1[j*4+3] = (short)f32_to_bf16_bits(f[j+2].w);
  }
  out[i * 2 + 0] = o0;
  out[i * 2 + 1] = o1;
}

// Barrier-free, LDS-free: one wave per 64x64 tile of sim = X·X^T, fragments
// loaded straight from global into MFMA layout (16B/lane), register ping-pong
// across the 16 K-steps. No __syncthreads -> no vmcnt(0) drains; the compiler
// schedules fine-grained vmcnt waits and waves stay runnable.
__launch_bounds__(64, 3)
__global__ void loss_kernel(const ushort* __restrict__ Xb, const int* __restrict__ tg,
                            float* __restrict__ out) {
  // triangular decode over 128-tile grid: start(bi) = 128*bi - bi*(bi-1)/2
  int t = blockIdx.x;
  int bi = (int)(128.5f - sqrtf(16512.25f - 2.0f * (float)t));
  if (bi < 0) bi = 0; if (bi > 127) bi = 127;
  while (bi > 0   && (128 * bi - (bi * (bi - 1)) / 2) > t) bi--;
  while (bi < 127 && (128 * (bi + 1) - ((bi + 1) * bi) / 2) <= t) bi++;
  const int bj = bi + (t - (128 * bi - (bi * (bi - 1)) / 2));

  const int lane = threadIdx.x & 63;
  const int quad = lane >> 4;
  const int l16  = lane & 15;

  const int rowBase = bi * 64;
  const int colBase = bj * 64;

  // element offsets into Xb for each fragment's base (k=0); 32-bit -> saddr form
  unsigned aoff[4], boff[4];
#pragma unroll
  for (int mt = 0; mt < 4; mt++)
    aoff[mt] = (unsigned)((rowBase + mt * 16 + l16) * NDIM + quad * 8);
#pragma unroll
  for (int nt = 0; nt < 4; nt++)
    boff[nt] = (unsigned)((colBase + nt * 16 + l16) * NDIM + quad * 8);

  floatx4 acc[4][4];
#pragma unroll
  for (int a = 0; a < 4; a++)
#pragma unroll
    for (int b = 0; b < 4; b++) acc[a][b] = (floatx4)(0.f);

  shortx8 af[2][4], bf[2][4];
#pragma unroll
  for (int mt = 0; mt < 4; mt++) af[0][mt] = *(const shortx8*)(Xb + aoff[mt]);
#pragma unroll
  for (int nt = 0; nt < 4; nt++) bf[0][nt] = *(const shortx8*)(Xb + boff[nt]);

#pragma unroll
  for (int kt = 0; kt < 16; kt++) {
    const int cur = kt & 1;
    if (kt < 15) {
      const int nk = (kt + 1) * 32;   // folds into global_load immediate offset
#pragma unroll
      for (int mt = 0; mt < 4; mt++) af[cur ^ 1][mt] = *(const shortx8*)(Xb + aoff[mt] + nk);
#pragma unroll
      for (int nt = 0; nt < 4; nt++) bf[cur ^ 1][nt] = *(const shortx8*)(Xb + boff[nt] + nk);
    }
#pragma unroll
    for (int mt = 0; mt < 4; mt++)
#pragma unroll
      for (int nt = 0; nt < 4; nt++)
        acc[mt][nt] = __builtin_amdgcn_mfma_f32_16x16x32_bf16(af[cur][mt], bf[cur][nt],
                                                              acc[mt][nt], 0, 0, 0);
  }

  // Epilogue. C/D layout: col = lane&15 (B/n index), row = quad*4 + reg (A/m index)
  float lsum = 0.f;
  const bool diag = (bi == bj);
#pragma unroll
  for (int mt = 0; mt < 4; mt++) {
    const int rloc = mt * 16 + quad * 4;
    const int4 rl = *(const int4*)(tg + rowBase + rloc);   // labels of 4 rows
    const int rlab[4] = {rl.x, rl.y, rl.z, rl.w};
#pragma unroll
    for (int nt = 0; nt < 4; nt++) {
      const int cloc = nt * 16 + l16;
      const int tc = tg[colBase + cloc];
      const int col = colBase + cloc;
#pragma unroll
      for (int r = 0; r < 4; r++) {
        const float s = acc[mt][nt][r];
        const int tr = rlab[r];
        float c = (tr == tc) ? ((s < 1.f) ? 1.f - s : 0.f)
                             : ((s > MARGIN) ? s : 0.f);
        float wgt;
        if (!diag) {
          wgt = 2.f;
        } else {
          const int row = rowBase + rloc + r;
          wgt = (row < col) ? 2.f : ((row == col) ? 1.f : 0.f);
        }
        lsum += wgt * c;
      }
    }
  }

#pragma unroll
  for (int off = 32; off > 0; off >>= 1) lsum += __shfl_down(lsum, off, 64);
  if (lane == 0) atomicAdd(out, lsum * (1.0f / NROWS));
}

extern "C" void kernel_launch(void* const* d_in, const int* in_sizes, int n_in,
                              void* d_out, int out_size, void* d_ws, size_t ws_size,
                              hipStream_t stream) {
  const float* x = (const float*)d_in[0];
  const int* tg  = (const int*)d_in[1];
  float* out     = (float*)d_out;
  ushort* xb     = (ushort*)d_ws;   // bf16 X, 8 MiB

  convert_kernel<<<(NROWS * NDIM / 16) / 256, 256, 0, stream>>>(
      (const float4*)x, (shortx8*)xb, out);
  loss_kernel<<<NT, 64, 0, stream>>>(xb, tg, out);
}

// Round 4
// 139.999 us; speedup vs baseline: 1.9039x; 1.9039x over previous
//
#include <hip/hip_runtime.h>
#include <hip/hip_bf16.h>
#include <stdint.h>

#define NROWS 8192
#define NDIM  512
#define MARGIN 0.3f
#define NT    2080     // 64*65/2 upper-triangular 128x128 blocks

typedef __attribute__((ext_vector_type(4))) float floatx4;
typedef __attribute__((ext_vector_type(8))) short shortx8;

__device__ inline unsigned short f32_to_bf16_bits(float x) {
  union { float f; unsigned int u; } v; v.f = x;
  unsigned int r = v.u + 0x7FFFu + ((v.u >> 16) & 1u);  // RNE
  return (unsigned short)(r >> 16);
}

// fp32 -> bf16, 16 floats per thread; also zeroes the (poisoned) output scalar
__global__ void convert_kernel(const float4* __restrict__ in, shortx8* __restrict__ out,
                               float* __restrict__ loss_out) {
  int i = blockIdx.x * blockDim.x + threadIdx.x;
  if (i == 0) loss_out[0] = 0.f;
  float4 f[4];
#pragma unroll
  for (int j = 0; j < 4; j++) f[j] = in[i * 4 + j];
  shortx8 o0, o1;
#pragma unroll
  for (int j = 0; j < 2; j++) {
    o0[j*4+0] = (short)f32_to_bf16_bits(f[j].x);
    o0[j*4+1] = (short)f32_to_bf16_bits(f[j].y);
    o0[j*4+2] = (short)f32_to_bf16_bits(f[j].z);
    o0[j*4+3] = (short)f32_to_bf16_bits(f[j].w);
    o1[j*4+0] = (short)f32_to_bf16_bits(f[j+2].x);
    o1[j*4+1] = (short)f32_to_bf16_bits(f[j+2].y);
    o1[j*4+2] = (short)f32_to_bf16_bits(f[j+2].z);
    o1[j*4+3] = (short)f32_to_bf16_bits(f[j+2].w);
  }
  out[i * 2 + 0] = o0;
  out[i * 2 + 1] = o1;
}

__device__ inline void gload_lds16(const void* g, void* l) {
  __builtin_amdgcn_global_load_lds(
      (const __attribute__((address_space(1))) unsigned int*)g,
      (__attribute__((address_space(3))) unsigned int*)l, 16, 0, 0);
}

// 128x128 upper-tri blocks of sim = X·X^T, bf16 MFMA.
// Single-buffered 32 KB swizzled LDS (4-5 blocks/CU: inter-block overlap hides
// the barrier vmcnt drains). blockIdx grouped into 8x8-tile super-blocks whose
// 2 MB working set fits one XCD L2 (consecutive ids round-robin across XCDs).
__launch_bounds__(256)
__global__ void loss_kernel(const ushort* __restrict__ Xb, const int* __restrict__ tg,
                            float* __restrict__ out) {
  __shared__ ushort As[128 * 64];   // 16 KB
  __shared__ ushort Bs[128 * 64];   // 16 KB

  // super-tile decode: 8 diagonal supers (36 blocks each, inner upper-tri),
  // then 28 off-diagonal supers (64 blocks each, row-major)
  int t = blockIdx.x;
  int bi, bj;
  if (t < 288) {
    int si = t / 36;
    int q  = t - si * 36;
    int ii = 0;
    while (q >= 8 - ii) { q -= 8 - ii; ii++; }
    bi = si * 8 + ii;
    bj = si * 8 + ii + q;
  } else {
    int q = t - 288;
    int s = q >> 6;          // 0..27 strict-upper 8x8 super grid, row-major
    int r = q & 63;
    int si = 0;
    while (s >= 7 - si) { s -= 7 - si; si++; }
    int sj = si + 1 + s;
    bi = si * 8 + (r >> 3);
    bj = sj * 8 + (r & 7);
  }

  const int tid  = threadIdx.x;
  const int lane = tid & 63;
  const int w    = tid >> 6;
  const int wm   = w >> 1, wn = w & 1;   // 2x2 waves, 64x64 each
  const int quad = lane >> 4;
  const int l16  = lane & 15;

  const int rowBase = bi * 128;
  const int colBase = bj * 128;

  // staging: 16 chunks of 512 elems (8 rows) per 128x64 tile; lane holds 8
  // elems; stored 16B slot (lane&7) corresponds to global slot sc ^ (r&7)
  const int sr = lane >> 3;
  const int sc = lane & 7;

  floatx4 acc[4][4];
#pragma unroll
  for (int a = 0; a < 4; a++)
#pragma unroll
    for (int b = 0; b < 4; b++) acc[a][b] = (floatx4)(0.f);

  for (int k0 = 0; k0 < NDIM; k0 += 64) {
    __syncthreads();          // previous iter's reads done
#pragma unroll
    for (int it = 0; it < 4; it++) {
      int chunk = it * 4 + w;
      int r = (chunk << 3) + sr;
      int cg = sc ^ (r & 7);
      gload_lds16(Xb + (size_t)(rowBase + r) * NDIM + k0 + cg * 8, As + chunk * 512);
      gload_lds16(Xb + (size_t)(colBase + r) * NDIM + k0 + cg * 8, Bs + chunk * 512);
    }
    __syncthreads();          // staging visible

#pragma unroll
    for (int kk = 0; kk < 2; kk++) {
      shortx8 a[4], b[4];
      const int kc = kk * 4 + quad;            // logical 16B chunk 0..7
#pragma unroll
      for (int mt = 0; mt < 4; mt++) {
        const int row = wm * 64 + mt * 16 + l16;
        a[mt] = *(const shortx8*)(&As[row * 64 + ((kc ^ (row & 7)) << 3)]);
      }
#pragma unroll
      for (int nt = 0; nt < 4; nt++) {
        const int row = wn * 64 + nt * 16 + l16;
        b[nt] = *(const shortx8*)(&Bs[row * 64 + ((kc ^ (row & 7)) << 3)]);
      }
#pragma unroll
      for (int mt = 0; mt < 4; mt++)
#pragma unroll
        for (int nt = 0; nt < 4; nt++)
          acc[mt][nt] = __builtin_amdgcn_mfma_f32_16x16x32_bf16(a[mt], b[nt], acc[mt][nt], 0, 0, 0);
    }
  }

  // Epilogue. C/D layout: col = lane&15, row = quad*4 + reg
  float lsum = 0.f;
  const bool diag = (bi == bj);
#pragma unroll
  for (int mt = 0; mt < 4; mt++) {
    const int rloc = wm * 64 + mt * 16 + quad * 4;
    const int4 rl = *(const int4*)(tg + rowBase + rloc);
    const int rlab[4] = {rl.x, rl.y, rl.z, rl.w};
#pragma unroll
    for (int nt = 0; nt < 4; nt++) {
      const int cloc = wn * 64 + nt * 16 + l16;
      const int tc = tg[colBase + cloc];
      const int col = colBase + cloc;
#pragma unroll
      for (int r = 0; r < 4; r++) {
        const float s = acc[mt][nt][r];
        float c = (rlab[r] == tc) ? ((s < 1.f) ? 1.f - s : 0.f)
                                  : ((s > MARGIN) ? s : 0.f);
        float wgt;
        if (!diag) {
          wgt = 2.f;
        } else {
          const int row = rowBase + rloc + r;
          wgt = (row < col) ? 2.f : ((row == col) ? 1.f : 0.f);
        }
        lsum += wgt * c;
      }
    }
  }

#pragma unroll
  for (int off = 32; off > 0; off >>= 1) lsum += __shfl_down(lsum, off, 64);

  __syncthreads();                       // done reading As; reuse as reduce scratch
  float* red = (float*)As;
  if (lane == 0) red[w] = lsum;
  __syncthreads();
  if (tid == 0)
    atomicAdd(out, (red[0] + red[1] + red[2] + red[3]) * (1.0f / NROWS));
}

extern "C" void kernel_launch(void* const* d_in, const int* in_sizes, int n_in,
                              void* d_out, int out_size, void* d_ws, size_t ws_size,
                              hipStream_t stream) {
  const float* x = (const float*)d_in[0];
  const int* tg  = (const int*)d_in[1];
  float* out     = (float*)d_out;
  ushort* xb     = (ushort*)d_ws;   // bf16 X, 8 MiB

  convert_kernel<<<(NROWS * NDIM / 16) / 256, 256, 0, stream>>>(
      (const float4*)x, (shortx8*)xb, out);
  loss_kernel<<<NT, 256, 0, stream>>>(xb, tg, out);
}